// Round 2
// 235.807 us; speedup vs baseline: 1.0037x; 1.0037x over previous
//
#include <hip/hip_runtime.h>
#include <hip/hip_bf16.h>
#include <math.h>

#define BB 2
#define AA 120000
#define CC 80
#define K_PRE 500
#define MAX_DET 300
#define CAP 2048
#define NB2 256                       // score bins (u16-packed, 2 per u32)
#define NBW 128                       // u32 words per class histogram
#define HB 960                        // hist/gather blocks (480 per image)
#define QTOT (BB * AA * 20)           // 4,800,000 float4 quads
#define QPB (QTOT / HB)               // 5,000 quads per block
#define LBUF 3072                     // per-block LDS candidate buffer
#define SPLIT 4                       // mask-kernel blocks per (b,c)

// ---------------- workspace layout (bytes) ----------------
// Base (proven, 6,784,640 B total):
#define OFF_BOXES   0
#define OFF_VALID   3840000
#define OFF_HIST    4080000
#define OFF_CNT     4161920
#define OFF_CUT     4162560
#define OFF_CAND    4163200           // 160*2048*8 = 2,621,440 -> end 6,784,640
// Split-path extras. supT ALIASES [0..5,242,880): boxes/valid/hist/cnt/cut and
// the cand prefix are all dead once k_sort completes (k_mask/k_greedy read only
// sbox/sscore/nv). sbox/sscore/nv append past the base region.
#define OFF_SUPT    0                 // 160*4096*8 = 5,242,880
#define OFF_SBOX    6784640           // 160*512*16 = 1,310,720 -> 8,095,360
#define OFF_SSC     8095360           // 160*512*4  =   327,680 -> 8,423,040
#define OFF_NV      8423040           // 160*4      =       640 -> 8,423,680
#define WS_SPLIT    8423680
#define ZERO_WORDS  20640   // hist (BB*CC*NBW = 20480 w) + cnt (160 w), contiguous

// ---------------- K1: decode + clip + valid, zero hist/cnt ----------------
__global__ __launch_bounds__(256) void k_decode(
    const float* __restrict__ deltas, const float* __restrict__ anchors,
    const int* __restrict__ ih, const int* __restrict__ iw,
    float* __restrict__ boxes, unsigned char* __restrict__ valid,
    unsigned int* __restrict__ zero_base)
{
    int tid = blockIdx.x * 256 + threadIdx.x;
    if (tid < ZERO_WORDS) zero_base[tid] = 0u;
    if (tid >= BB * AA) return;

    float4 d  = ((const float4*)deltas)[tid];
    float4 an = ((const float4*)anchors)[tid];

    const float CLAMPF = (float)4.135166556742356;  // float(log(1000/16))
    double W = (double)(*iw);
    double H = (double)(*ih);

    double aw  = (double)an.z - (double)an.x;
    double ah  = (double)an.w - (double)an.y;
    double acx = (double)an.x + 0.5 * aw;
    double acy = (double)an.y + 0.5 * ah;

    double dw = fmin((double)d.z, (double)CLAMPF);
    double dh = fmin((double)d.w, (double)CLAMPF);

    double pcx = (double)d.x * aw + acx;
    double pcy = (double)d.y * ah + acy;
    double pw  = exp(dw) * aw;
    double ph  = exp(dh) * ah;

    float x1 = (float)fmin(fmax(pcx - 0.5 * pw, 0.0), W);
    float y1 = (float)fmin(fmax(pcy - 0.5 * ph, 0.0), H);
    float x2 = (float)fmin(fmax(pcx + 0.5 * pw, 0.0), W);
    float y2 = (float)fmin(fmax(pcy + 0.5 * ph, 0.0), H);

    float4 bb; bb.x = x1; bb.y = y1; bb.z = x2; bb.w = y2;
    ((float4*)boxes)[tid] = bb;
    valid[tid] = (((x2 - x1) >= 0.01f) && ((y2 - y1) >= 0.01f)) ? 1 : 0;
}

// ---------------- K2: coalesced score histogram, 256 bins u16-packed ------
__global__ __launch_bounds__(256) void k_hist(
    const float* __restrict__ scores, const unsigned char* __restrict__ valid,
    unsigned int* __restrict__ hist)
{
    __shared__ unsigned int lh[CC * NBW];   // 40 KB

    int blk   = blockIdx.x;
    int b     = blk / (HB / BB);
    int start = blk * QPB;
    int end   = start + QPB;

    for (int i = threadIdx.x; i < CC * NBW; i += 256) lh[i] = 0u;
    __syncthreads();

    const float4* s4 = (const float4*)scores;

    for (int i0 = start + threadIdx.x; i0 < end; i0 += 1024) {
        int   ids[4];
        bool  has[4];
        float4 s[4];
        unsigned char vs[4];
        #pragma unroll
        for (int u = 0; u < 4; ++u) {
            int id = i0 + u * 256;
            has[u] = id < end;
            ids[u] = has[u] ? id : start;
        }
        #pragma unroll
        for (int u = 0; u < 4; ++u) s[u] = s4[ids[u]];
        #pragma unroll
        for (int u = 0; u < 4; ++u) vs[u] = valid[ids[u] / 20];
        #pragma unroll
        for (int u = 0; u < 4; ++u) {
            if (has[u] && vs[u]) {
                int q = ids[u] % 20;
                unsigned int* lb = &lh[(4 * q) * NBW];
                float cv[4] = {s[u].x, s[u].y, s[u].z, s[u].w};
                #pragma unroll
                for (int cl = 0; cl < 4; ++cl) {
                    float sc = cv[cl];
                    if (sc > 0.05f) {
                        int bn = min((int)(sc * 256.0f), 255);
                        atomicAdd(&lb[cl * NBW + (bn >> 1)], (bn & 1) ? 65536u : 1u);
                    }
                }
            }
        }
    }
    __syncthreads();

    unsigned int* gh = hist + (size_t)b * CC * NBW;
    for (int i = threadIdx.x; i < CC * NBW; i += 256) {
        unsigned int v = lh[i];
        if (v) atomicAdd(&gh[i], v);   // packed halves; totals < 65536 per half
    }
}

// ---------------- K3: find cut bin per (b,c), 256 bins -------------------
__global__ __launch_bounds__(256) void k_cut(
    const unsigned int* __restrict__ hist, int* __restrict__ cutbin)
{
    __shared__ unsigned int hw[NBW];
    __shared__ int best;
    int bc = blockIdx.x;
    int t  = threadIdx.x;
    if (t < NBW) hw[t] = hist[(size_t)bc * NBW + t];
    if (t == 0) best = 0;
    __syncthreads();
    unsigned int s = 0;
    for (int j = t; j < NB2; ++j)
        s += (hw[j >> 1] >> ((j & 1) * 16)) & 0xFFFFu;   // suffix sum at t
    if (s >= K_PRE) atomicMax(&best, t);
    __syncthreads();
    if (t == 0) cutbin[bc] = best;
}

// ---------------- K4: gather with LDS staging + block reservation --------
__global__ __launch_bounds__(256) void k_gather(
    const float* __restrict__ scores, const unsigned char* __restrict__ valid,
    const int* __restrict__ cutbin, unsigned int* __restrict__ cnt,
    unsigned long long* __restrict__ cand)
{
    __shared__ int lcut[CC];
    __shared__ unsigned int lcnt[CC];
    __shared__ unsigned int lbase[CC];
    __shared__ unsigned long long lkey[LBUF];   // 24 KB
    __shared__ unsigned short lcls[LBUF];       // 6 KB
    __shared__ unsigned int ltot;

    int blk   = blockIdx.x;
    int b     = blk / (HB / BB);
    int start = blk * QPB;
    int end   = start + QPB;

    if (threadIdx.x < CC) {
        lcut[threadIdx.x] = cutbin[b * CC + threadIdx.x];
        lcnt[threadIdx.x] = 0u;
    }
    if (threadIdx.x == 255) ltot = 0u;
    __syncthreads();

    const float4* s4 = (const float4*)scores;

    for (int i0 = start + threadIdx.x; i0 < end; i0 += 1024) {
        int   ids[4];
        bool  has[4];
        float4 s[4];
        unsigned char vs[4];
        #pragma unroll
        for (int u = 0; u < 4; ++u) {
            int id = i0 + u * 256;
            has[u] = id < end;
            ids[u] = has[u] ? id : start;
        }
        #pragma unroll
        for (int u = 0; u < 4; ++u) s[u] = s4[ids[u]];
        #pragma unroll
        for (int u = 0; u < 4; ++u) vs[u] = valid[ids[u] / 20];
        #pragma unroll
        for (int u = 0; u < 4; ++u) {
            if (has[u] && vs[u]) {
                int ga = ids[u] / 20;
                int c0 = 4 * (ids[u] % 20);
                unsigned long long lokey =
                    (unsigned long long)(~(unsigned int)(ga - b * AA));
                float cv[4] = {s[u].x, s[u].y, s[u].z, s[u].w};
                #pragma unroll
                for (int cl = 0; cl < 4; ++cl) {
                    float sc = cv[cl];
                    if (sc > 0.05f) {
                        int bn = min((int)(sc * 256.0f), 255);
                        int c  = c0 + cl;
                        if (bn >= lcut[c]) {
                            unsigned int p = atomicAdd(&ltot, 1u);
                            if (p < LBUF) {
                                lkey[p] = (((unsigned long long)__float_as_uint(sc)) << 32) | lokey;
                                lcls[p] = (unsigned short)c;
                                atomicAdd(&lcnt[c], 1u);
                            }
                        }
                    }
                }
            }
        }
    }
    __syncthreads();

    if (threadIdx.x < CC) {
        unsigned int nn = lcnt[threadIdx.x];
        if (nn) lbase[threadIdx.x] = atomicAdd(&cnt[b * CC + threadIdx.x], nn);
    }
    __syncthreads();

    unsigned int tot = min(ltot, (unsigned int)LBUF);
    for (unsigned int i = threadIdx.x; i < tot; i += 256) {
        int c = lcls[i];
        unsigned int pos = atomicAdd(&lbase[c], 1u);
        if (pos < CAP)
            cand[((size_t)(b * CC + c)) * CAP + pos] = lkey[i];
    }
}

// ---------------- K5a: bitonic sort, write compacted top-512 --------------
// double-buffered LDS passes: 1 barrier per j>=64 pass (10 total for n<=1024,
// 14 for the 2048 fallback which keeps 2 elems/thread in registers).
__global__ __launch_bounds__(1024) void k_sort(
    const float* __restrict__ boxes, const unsigned int* __restrict__ cnt,
    const unsigned long long* __restrict__ cand,
    float4* __restrict__ sbox, float* __restrict__ sscore, int* __restrict__ nvout)
{
    __shared__ unsigned long long kb[2][2048];   // 32 KB double buffer

    int bc = blockIdx.x;
    int b  = bc / CC;
    int n  = (int)min(cnt[bc], (unsigned int)CAP);
    int i  = threadIdx.x;
    const unsigned long long* cp = cand + (size_t)bc * CAP;

    unsigned long long key;

    if (n <= 1024) {
        key = (i < n) ? cp[i] : 0ull;
        int p = 0;
        for (unsigned int k = 2; k <= 1024; k <<= 1) {
            bool up = ((i & k) == 0);
            for (unsigned int j = k >> 1; j > 0; j >>= 1) {
                unsigned long long other;
                if (j >= 64) {
                    kb[p][i] = key;
                    __syncthreads();
                    other = kb[p][i ^ j];
                    p ^= 1;                      // WAR-safe: same buffer rewritten
                } else {                         // only after an intervening barrier
                    other = __shfl_xor(key, (int)j);
                }
                bool lower = ((i & j) == 0);
                bool keep_max = (lower == up);   // descending in "up" region
                bool mine_big = key > other;
                key = (keep_max == mine_big) ? key : other;
            }
        }
    } else {
        // 2048 fallback: 2 elements/thread (t=i and t=i+1024), hybrid passes
        unsigned long long kA = (i < n) ? cp[i] : 0ull;
        unsigned long long kB = (i + 1024 < n) ? cp[i + 1024] : 0ull;
        int tA = i, tB = i + 1024;
        int p = 0;
        for (unsigned int k = 2; k <= 2048; k <<= 1) {
            for (unsigned int j = k >> 1; j > 0; j >>= 1) {
                if (j == 1024) {
                    // partner is own pair; k=2048 => up=true, tA lower => keep max
                    unsigned long long mx = (kA > kB) ? kA : kB;
                    unsigned long long mn = (kA > kB) ? kB : kA;
                    kA = mx; kB = mn;
                } else if (j >= 64) {
                    kb[p][tA] = kA; kb[p][tB] = kB;
                    __syncthreads();
                    unsigned long long oA = kb[p][tA ^ (int)j];
                    unsigned long long oB = kb[p][tB ^ (int)j];
                    p ^= 1;
                    { bool up = ((tA & k) == 0), lo = ((tA & j) == 0);
                      bool km = (lo == up), mb = kA > oA; kA = (km == mb) ? kA : oA; }
                    { bool up = ((tB & k) == 0), lo = ((tB & j) == 0);
                      bool km = (lo == up), mb = kB > oB; kB = (km == mb) ? kB : oB; }
                } else {
                    unsigned long long oA = __shfl_xor(kA, (int)j);
                    unsigned long long oB = __shfl_xor(kB, (int)j);
                    { bool up = ((tA & k) == 0), lo = ((tA & j) == 0);
                      bool km = (lo == up), mb = kA > oA; kA = (km == mb) ? kA : oA; }
                    { bool up = ((tB & k) == 0), lo = ((tB & j) == 0);
                      bool km = (lo == up), mb = kB > oB; kB = (km == mb) ? kB : oB; }
                }
            }
        }
        key = kA;   // element i (descending) — top-1024 live in kA across threads
    }

    // compacted write: sorted boxes (coalesced for downstream kernels) + scores
    if (i < 512) {
        bool v = (key != 0ull);
        float sc = v ? __uint_as_float((unsigned int)(key >> 32)) : -1.0f;
        int a = v ? (int)(~(unsigned int)key) : 0;
        float4 bb = make_float4(0.f, 0.f, 0.f, 0.f);
        if (v && i < K_PRE) bb = ((const float4*)boxes)[(size_t)b * AA + a];
        sbox[(size_t)bc * 512 + i] = bb;
        sscore[(size_t)bc * 512 + i] = sc;
    }
    if (i == 0) nvout[bc] = min(n, K_PRE);
}

// ---------------- K5b: suppression masks, 4 blocks per (b,c) --------------
// 640 blocks x 512 threads -> all 256 CUs busy. Wave w owns i-word w;
// it only visits j >= 64*w; greedy only reads (j, w2) with w2 <= j>>6, so
// every read word is written by exactly one of the SPLIT blocks.
__global__ __launch_bounds__(512) void k_mask(
    const float4* __restrict__ sbox, const int* __restrict__ nvg,
    unsigned long long* __restrict__ supTg)
{
    __shared__ float4 box4[512];    // 8 KB
    __shared__ float  ar[512];      // 2 KB

    int bc = blockIdx.x >> 2;
    int s  = blockIdx.x & (SPLIT - 1);
    int tid = threadIdx.x;

    float4 bl = sbox[(size_t)bc * 512 + tid];
    box4[tid] = bl;
    ar[tid] = (bl.z - bl.x) * (bl.w - bl.y);
    __syncthreads();

    int nv = nvg[bc];
    int wave = tid >> 6, lane = tid & 63;
    int ii = tid;                    // i = wave*64 + lane
    float4 bi = box4[ii];
    float ia = ar[ii];
    unsigned long long* sp = supTg + (size_t)bc * 512 * 8;

    for (int j = wave * 64 + s; j < 512; j += SPLIT) {
        float4 bj = box4[j];         // wave-uniform broadcast
        float ja = ar[j];
        bool p = false;
        if (ii < j && j < nv) {
            float ltx = fmaxf(bi.x, bj.x);
            float lty = fmaxf(bi.y, bj.y);
            float rbx = fminf(bi.z, bj.z);
            float rby = fminf(bi.w, bj.w);
            float wx = fmaxf(rbx - ltx, 0.0f);
            float wy = fmaxf(rby - lty, 0.0f);
            float inter = wx * wy;
            float iou = inter / fmaxf(ia + ja - inter, 1e-9f);
            p = iou > 0.5f;
        }
        unsigned long long m = __ballot(p);
        if (lane == 0) sp[(size_t)j * 8 + wave] = m;
    }
}

// ---------------- K5c: greedy keep + compaction/output --------------------
__global__ __launch_bounds__(512) void k_greedy(
    const float4* __restrict__ sbox, const float* __restrict__ sscore,
    const int* __restrict__ nvg, const unsigned long long* __restrict__ supTg,
    float* __restrict__ out)
{
    __shared__ unsigned long long supT[512 * 9];    // 36 KB (+1 word pad: 4-way banks)
    __shared__ float4 box4[512];                    // 8 KB
    __shared__ float  scs[512];                     // 2 KB
    __shared__ unsigned long long keepsh[8];
    __shared__ int pfx[9];

    int bc = blockIdx.x;
    int tid = threadIdx.x;
    int nv = nvg[bc];

    box4[tid] = sbox[(size_t)bc * 512 + tid];
    scs[tid]  = sscore[(size_t)bc * 512 + tid];
    const unsigned long long* sp = supTg + (size_t)bc * 4096;
    for (int t = tid; t < 4096; t += 512)
        supT[(t >> 3) * 9 + (t & 7)] = sp[t];
    __syncthreads();

    // exact greedy: word-blocked Gauss-Seidel, intra-word bounded Jacobi.
    if (tid < 64) {
        int l = tid;
        unsigned long long kept[8];
        #pragma unroll
        for (int w = 0; w < 8; ++w) {
            int j = w * 64 + l;
            bool vj = j < nv;
            bool ext = false;
            #pragma unroll
            for (int w2 = 0; w2 < 8; ++w2)
                if (w2 < w) ext = ext || ((supT[j * 9 + w2] & kept[w2]) != 0ull);
            unsigned long long intra = supT[j * 9 + w];   // bits i<j only
            bool base = vj && !ext;
            unsigned long long kw = __ballot(base);
            for (int r = 0; r < 64; ++r) {                // depth <= 64 => exact
                bool k2 = base && ((intra & kw) == 0ull);
                unsigned long long nkw = __ballot(k2);
                if (nkw == kw) break;
                kw = nkw;
            }
            kept[w] = kw;
        }
        if (l < 8) keepsh[l] = kept[l];
    }
    __syncthreads();

    if (tid == 0) {
        int s = 0;
        for (int w = 0; w < 8; ++w) { pfx[w] = s; s += __popcll(keepsh[w]); }
        pfx[8] = s;
    }
    __syncthreads();

    // compaction: kept first (score order), then non-kept (score order)
    int total_kept = pfx[8];
    if (tid < K_PRE) {
        int t = tid;
        int w = t >> 6, bit = t & 63;
        unsigned long long kw = keepsh[w];
        bool kv = (kw >> bit) & 1ull;
        int kb2 = pfx[w] + __popcll(kw & ((bit == 0) ? 0ull : ((1ull << bit) - 1ull)));
        int p = kv ? kb2 : (total_kept + (t - kb2));
        if (p < MAX_DET) {
            float* o = out + ((size_t)bc * MAX_DET + p) * 5;
            if (kv) {
                float4 bb = box4[t];
                o[0] = bb.x; o[1] = bb.y; o[2] = bb.z; o[3] = bb.w; o[4] = scs[t];
            } else {
                o[0] = 0.f; o[1] = 0.f; o[2] = 0.f; o[3] = 0.f; o[4] = -1.0f;
            }
        }
    }
}

// ---------------- K5 (fallback): fused sort + NMS, proven 6.78 MB layout --
__global__ __launch_bounds__(1024) void k_nms(
    const float* __restrict__ boxes, const unsigned int* __restrict__ cnt,
    const unsigned long long* __restrict__ cand, float* __restrict__ out)
{
    __shared__ unsigned long long keys[CAP];        // 16 KB
    __shared__ float4 box4[512];                    // 8 KB
    __shared__ float ar[512], scs[512];             // 4 KB
    __shared__ unsigned long long supT[512 * 8];    // 32 KB
    __shared__ unsigned long long keepsh[8];
    __shared__ int pfx[9];

    int bc = blockIdx.x;
    int b  = bc / CC;
    int n  = (int)min(cnt[bc], (unsigned int)CAP);
    int i  = threadIdx.x;

    const unsigned long long* cp = cand + (size_t)bc * CAP;

    if (n <= 1024) {
        unsigned long long key = (i < n) ? cp[i] : 0ull;
        for (unsigned int k = 2; k <= 1024; k <<= 1) {
            bool up = ((i & k) == 0);
            for (unsigned int j = k >> 1; j > 0; j >>= 1) {
                unsigned long long other;
                if (j >= 64) {
                    keys[i] = key;
                    __syncthreads();
                    other = keys[i ^ j];
                    __syncthreads();
                } else {
                    other = __shfl_xor(key, (int)j);
                }
                bool lower = ((i & j) == 0);
                bool keep_max = (lower == up);
                bool mine_big = key > other;
                key = (keep_max == mine_big) ? key : other;
            }
        }
        keys[i] = key;
        __syncthreads();
    } else {
        for (int t = i; t < CAP; t += 1024)
            keys[t] = (t < n) ? cp[t] : 0ull;
        for (unsigned int k = 2; k <= (unsigned int)CAP; k <<= 1) {
            for (unsigned int j = k >> 1; j > 0; j >>= 1) {
                __syncthreads();
                for (unsigned int t = i; t < (unsigned int)CAP; t += 1024) {
                    unsigned int txj = t ^ j;
                    if (txj > t) {
                        unsigned long long a = keys[t], bk = keys[txj];
                        bool up = ((t & k) == 0);
                        if (up ? (a < bk) : (a > bk)) { keys[t] = bk; keys[txj] = a; }
                    }
                }
            }
        }
        __syncthreads();
    }

    if (i < 512) {
        unsigned long long key = keys[i];
        bool v = (key != 0ull);
        scs[i] = v ? __uint_as_float((unsigned int)(key >> 32)) : -1.0f;
        int a = v ? (int)(~(unsigned int)key) : 0;
        float4 bb = make_float4(0.f, 0.f, 0.f, 0.f);
        if (v && i < K_PRE) bb = ((const float4*)boxes)[(size_t)b * AA + a];
        box4[i] = bb;
        ar[i] = (bb.z - bb.x) * (bb.w - bb.y);
    }
    for (int t = i; t < 512 * 8; t += 1024) supT[t] = 0ull;
    __syncthreads();

    int nv = min(n, K_PRE);

    {
        int wave = threadIdx.x >> 6;
        int lane = threadIdx.x & 63;
        for (int iw = 0; iw < 8; ++iw) {
            int ii = iw * 64 + lane;
            float4 bi = box4[ii];
            float ia = ar[ii];
            for (int j = iw * 64 + wave; j < 512; j += 16) {
                float4 bj = box4[j];
                float ja = ar[j];
                bool p = false;
                if (ii < j && j < nv) {
                    float ltx = fmaxf(bi.x, bj.x);
                    float lty = fmaxf(bi.y, bj.y);
                    float rbx = fminf(bi.z, bj.z);
                    float rby = fminf(bi.w, bj.w);
                    float wx = fmaxf(rbx - ltx, 0.0f);
                    float wy = fmaxf(rby - lty, 0.0f);
                    float inter = wx * wy;
                    float iou = inter / fmaxf(ia + ja - inter, 1e-9f);
                    p = iou > 0.5f;
                }
                unsigned long long m = __ballot(p);
                if (lane == 0) supT[j * 8 + iw] = m;
            }
        }
    }
    __syncthreads();

    if (threadIdx.x < 64) {
        int l = threadIdx.x;
        unsigned long long kept[8];
        #pragma unroll
        for (int w = 0; w < 8; ++w) {
            int j = w * 64 + l;
            bool vj = j < nv;
            bool ext = false;
            #pragma unroll
            for (int w2 = 0; w2 < 8; ++w2)
                if (w2 < w) ext = ext || ((supT[j * 8 + w2] & kept[w2]) != 0ull);
            unsigned long long intra = supT[j * 8 + w];
            bool base = vj && !ext;
            unsigned long long kw = __ballot(base);
            for (int r = 0; r < 64; ++r) {
                bool k2 = base && ((intra & kw) == 0ull);
                unsigned long long nkw = __ballot(k2);
                if (nkw == kw) break;
                kw = nkw;
            }
            kept[w] = kw;
        }
        if (l < 8) keepsh[l] = kept[l];
    }
    __syncthreads();

    if (threadIdx.x == 0) {
        int s = 0;
        for (int w = 0; w < 8; ++w) { pfx[w] = s; s += __popcll(keepsh[w]); }
        pfx[8] = s;
    }
    __syncthreads();

    int total_kept = pfx[8];
    if (threadIdx.x < K_PRE) {
        int t = threadIdx.x;
        int w = t >> 6, bit = t & 63;
        unsigned long long kw = keepsh[w];
        bool kv = (kw >> bit) & 1ull;
        int kb2 = pfx[w] + __popcll(kw & ((bit == 0) ? 0ull : ((1ull << bit) - 1ull)));
        int p = kv ? kb2 : (total_kept + (t - kb2));
        if (p < MAX_DET) {
            float* o = out + ((size_t)bc * MAX_DET + p) * 5;
            if (kv) {
                float4 bb = box4[t];
                o[0] = bb.x; o[1] = bb.y; o[2] = bb.z; o[3] = bb.w; o[4] = scs[t];
            } else {
                o[0] = 0.f; o[1] = 0.f; o[2] = 0.f; o[3] = 0.f; o[4] = -1.0f;
            }
        }
    }
}

extern "C" void kernel_launch(void* const* d_in, const int* in_sizes, int n_in,
                              void* d_out, int out_size, void* d_ws, size_t ws_size,
                              hipStream_t stream)
{
    const float* deltas  = (const float*)d_in[0];
    const float* scores  = (const float*)d_in[1];
    const float* anchors = (const float*)d_in[2];
    const int*   ih      = (const int*)d_in[3];
    const int*   iw      = (const int*)d_in[4];
    float* out = (float*)d_out;

    char* w = (char*)d_ws;
    float*              boxes  = (float*)(w + OFF_BOXES);
    unsigned char*      valid  = (unsigned char*)(w + OFF_VALID);
    unsigned int*       hist   = (unsigned int*)(w + OFF_HIST);
    unsigned int*       cnt    = (unsigned int*)(w + OFF_CNT);
    int*                cutbin = (int*)(w + OFF_CUT);
    unsigned long long* cand   = (unsigned long long*)(w + OFF_CAND);

    int g1 = (BB * AA + 255) / 256;
    k_decode<<<g1, 256, 0, stream>>>(deltas, anchors, ih, iw, boxes, valid, hist);
    k_hist<<<HB, 256, 0, stream>>>(scores, valid, hist);
    k_cut<<<BB * CC, 256, 0, stream>>>(hist, cutbin);
    k_gather<<<HB, 256, 0, stream>>>(scores, valid, cutbin, cnt, cand);

    if (ws_size >= (size_t)WS_SPLIT) {
        // split path: supT aliases the dead boxes/valid/hist/cnt/cut/cand-prefix
        unsigned long long* supTg  = (unsigned long long*)(w + OFF_SUPT);
        float4*             sbox   = (float4*)(w + OFF_SBOX);
        float*              sscore = (float*)(w + OFF_SSC);
        int*                nv     = (int*)(w + OFF_NV);
        k_sort<<<BB * CC, 1024, 0, stream>>>(boxes, cnt, cand, sbox, sscore, nv);
        k_mask<<<BB * CC * SPLIT, 512, 0, stream>>>(sbox, nv, supTg);
        k_greedy<<<BB * CC, 512, 0, stream>>>(sbox, sscore, nv, supTg, out);
    } else {
        // fallback: proven fused kernel, base layout only (6,784,640 B)
        k_nms<<<BB * CC, 1024, 0, stream>>>(boxes, cnt, cand, out);
    }
}